// Round 12
// baseline (1190.180 us; speedup 1.0000x reference)
//
#include <hip/hip_runtime.h>
#include <hip/hip_cooperative_groups.h>

namespace cg = cooperative_groups;

#define NN 100000
#define NE 3200000
#define BS 512                      // nodes per bucket
#define NBUCK 196                   // ceil(NN/BS)
#define EPB 12500                   // edges per binA block (256 binA blocks)
#define NBLK 1024                   // coop grid: 4 blocks/CU x 256 CU
#define GEMM_BLKS 768               // P0 split: [0,768) gemm, [768,1024) binA
#define NTILE 1563                  // ceil(NN/64)

typedef short bf16x8 __attribute__((ext_vector_type(8)));
typedef float f32x4  __attribute__((ext_vector_type(4)));

__device__ inline unsigned rne_bf16(float x) {
    unsigned u = __float_as_uint(x);
    return (u + 0x7fffu + ((u >> 16) & 1u)) >> 16;   // round-to-nearest-even
}
__device__ inline float bflo(unsigned u) { return __uint_as_float(u << 16); }
__device__ inline float bfhi(unsigned u) { return __uint_as_float(u & 0xffff0000u); }

// ===========================================================================
// L1: fused {gemm_n16 (W2@W3 -> M1), 16 blocks} + {hist_coarse, 256 blocks}
// ===========================================================================
__global__ __launch_bounds__(256) void l1_gemm_hist(const float* __restrict__ W2,
                                                    const float* __restrict__ W3,
                                                    float* __restrict__ M1,
                                                    const int* __restrict__ dst,
                                                    int* __restrict__ cntA) {
    __shared__ float As[16][260];
    __shared__ float Bs[256][16];
    __shared__ int hh[NBUCK];
    const int t = threadIdx.x;

    if (blockIdx.x < 16) {
        const int block_row = blockIdx.x * 16;
        for (int i = t; i < 1024; i += 256)
            ((float4*)&Bs[0][0])[i] = ((const float4*)W3)[i];
        for (int i = t; i < 1024; i += 256) {
            int idx = i << 2;
            int r = idx >> 8, c = idx & 255;
            int row = block_row + r;
            float4 v = ((const float4*)(W2 + (size_t)row * 256))[c >> 2];
            *(float4*)&As[r][c] = v;
        }
        __syncthreads();
        const int r = t >> 4, c = t & 15;
        float acc = 0.f;
#pragma unroll 8
        for (int k = 0; k < 256; ++k) acc += As[r][k] * Bs[k][c];
        M1[(size_t)(block_row + r) * 16 + c] = acc;
    } else {
        const int hb = blockIdx.x - 16;   // 0..255
        for (int i = t; i < NBUCK; i += 256) hh[i] = 0;
        __syncthreads();
        for (int e = hb * 256 + t; e < NE; e += 256 * 256)
            atomicAdd(&hh[dst[e] >> 9], 1);
        __syncthreads();
        for (int i = t; i < NBUCK; i += 256)
            if (hh[i]) atomicAdd(&cntA[i], hh[i]);
    }
}

// ===========================================================================
// L2: gemm_n16t: WcT[16][512] bf16 = (W1[512][256] @ M1[256][16])^T
// ===========================================================================
__global__ __launch_bounds__(256) void gemm_n16t(const float* __restrict__ A,
                                                 const float* __restrict__ B,
                                                 unsigned short* __restrict__ Wt) {
    __shared__ float As[16][260];
    __shared__ float Bs[256][16];
    const int t = threadIdx.x;
    const int block_row = blockIdx.x * 16;

    for (int i = t; i < 1024; i += 256)
        ((float4*)&Bs[0][0])[i] = ((const float4*)B)[i];
    for (int i = t; i < 1024; i += 256) {
        int idx = i << 2;
        int r = idx >> 8, c = idx & 255;
        int row = block_row + r;
        float4 v = ((const float4*)(A + (size_t)row * 256))[c >> 2];
        *(float4*)&As[r][c] = v;
    }
    __syncthreads();
    const int r = t >> 4, c = t & 15;
    float acc = 0.f;
#pragma unroll 8
    for (int k = 0; k < 256; ++k) acc += As[r][k] * Bs[k][c];
    Wt[(size_t)c * 512 + block_row + r] = (unsigned short)rne_bf16(acc);
}

// ===========================================================================
// agg body: bf16 gather, fp32 accumulate; 4 threads/node, uint2 (4 feats)
// ===========================================================================
template<bool OUT_F32>
__device__ __forceinline__ void agg_body(int tid, const unsigned short* __restrict__ h,
                                         const int* __restrict__ offs,
                                         const int* __restrict__ srcs,
                                         void* __restrict__ outp) {
    int node = tid >> 2, f4 = tid & 3;
    int beg = offs[node], end = offs[node + 1];
    float a0 = 0, a1 = 0, a2 = 0, a3 = 0;
    float b0 = 0, b1 = 0, b2 = 0, b3 = 0;
    int j = beg;
    for (; j + 2 <= end; j += 2) {
        int s0 = srcs[j], s1 = srcs[j + 1];
        uint2 u = *(const uint2*)(h + (size_t)s0 * 16 + f4 * 4);
        uint2 v = *(const uint2*)(h + (size_t)s1 * 16 + f4 * 4);
        a0 += bflo(u.x); a1 += bfhi(u.x); a2 += bflo(u.y); a3 += bfhi(u.y);
        b0 += bflo(v.x); b1 += bfhi(v.x); b2 += bflo(v.y); b3 += bfhi(v.y);
    }
    if (j < end) {
        uint2 u = *(const uint2*)(h + (size_t)srcs[j] * 16 + f4 * 4);
        a0 += bflo(u.x); a1 += bfhi(u.x); a2 += bflo(u.y); a3 += bfhi(u.y);
    }
    float r0 = a0 + b0, r1 = a1 + b1, r2 = a2 + b2, r3 = a3 + b3;
    if (OUT_F32) {
        ((float4*)outp)[(size_t)node * 4 + f4] = make_float4(r0, r1, r2, r3);
    } else {
        uint2 r;
        r.x = rne_bf16(r0) | (rne_bf16(r1) << 16);
        r.y = rne_bf16(r2) | (rne_bf16(r3) << 16);
        ((uint2*)outp)[(size_t)node * 4 + f4] = r;
    }
}

// ===========================================================================
// Cooperative mega-kernel:
//   P0: gemm_xwc (blocks 0..767, grid-stride 64-row tiles) || binA (768..1023)
//   P1: binB (blocks 0..195, one bucket each)
//   P2: Gb = A*Yb   P3: Yb = A*Gb   P4: out = A*Yb (fp32)
// ===========================================================================
__global__ __launch_bounds__(256, 4) void mega(const int* __restrict__ src,
                                               const int* __restrict__ dst,
                                               const int* __restrict__ cntA,
                                               int* __restrict__ cursorCnt,
                                               unsigned* __restrict__ packed,
                                               const float* __restrict__ X,
                                               const unsigned short* __restrict__ WcT,
                                               unsigned short* __restrict__ Yb,
                                               unsigned short* __restrict__ Gb,
                                               int* __restrict__ offs,
                                               int* __restrict__ srcs,
                                               float* __restrict__ out) {
    cg::grid_group grid = cg::this_grid();
    const int blk = blockIdx.x;
    const int t = threadIdx.x;

    __shared__ union SM {
        struct { unsigned short As[64][72]; unsigned short Ws[16][520]; } g;   // 25856 B
        struct { int sscan[256]; int baseL[NBUCK]; int hist[NBUCK]; } a;
        struct { int sscan[256]; int h[512]; int run[512]; } b;
    } sm;

    // ======================= P0: gemm || binA =======================
    if (blk < GEMM_BLKS) {
        const int w = t >> 6, lane = t & 63;
        const int lrow = lane & 15, lk8 = (lane >> 4) * 8;
        // load WcT [16][512] into LDS once
        for (int idx = t; idx < 1024; idx += 256) {
            int row = idx >> 6, ch = idx & 63;
            *(uint4*)&sm.g.Ws[row][ch * 8] = ((const uint4*)(WcT + row * 512))[ch];
        }
        const int s_arow = t & 63, s_aq = t >> 6;   // 4 chunks of 16 halfs/row
        for (int tile = blk; tile < NTILE; tile += GEMM_BLKS) {
            const int brow = tile * 64;
            const bool arow_ok = (brow + s_arow) < NN;
            const float* Ap0 = X + (size_t)(brow + s_arow) * 512 + s_aq * 16;
            f32x4 acc = {};
            for (int k0 = 0; k0 < 512; k0 += 64) {
                float4 f[4];
                if (arow_ok) {
                    const float4* p = (const float4*)(Ap0 + k0);
#pragma unroll
                    for (int i = 0; i < 4; ++i) f[i] = p[i];
                } else {
#pragma unroll
                    for (int i = 0; i < 4; ++i) f[i] = make_float4(0.f, 0.f, 0.f, 0.f);
                }
                unsigned p8[8];
#pragma unroll
                for (int i = 0; i < 4; ++i) {
                    p8[2 * i]     = rne_bf16(f[i].x) | (rne_bf16(f[i].y) << 16);
                    p8[2 * i + 1] = rne_bf16(f[i].z) | (rne_bf16(f[i].w) << 16);
                }
                *(uint4*)&sm.g.As[s_arow][s_aq * 16]     = make_uint4(p8[0], p8[1], p8[2], p8[3]);
                *(uint4*)&sm.g.As[s_arow][s_aq * 16 + 8] = make_uint4(p8[4], p8[5], p8[6], p8[7]);
                __syncthreads();
#pragma unroll
                for (int ks = 0; ks < 2; ++ks) {
                    bf16x8 af = *(const bf16x8*)&sm.g.As[w * 16 + lrow][ks * 32 + lk8];
                    bf16x8 bw = *(const bf16x8*)&sm.g.Ws[lrow][k0 + ks * 32 + lk8];
                    acc = __builtin_amdgcn_mfma_f32_16x16x32_bf16(af, bw, acc, 0, 0, 0);
                }
                __syncthreads();
            }
            const int col = lrow;
            const int rbase = brow + w * 16 + (lane >> 4) * 4;
#pragma unroll
            for (int r = 0; r < 4; ++r) {
                int row = rbase + r;
                if (row < NN)
                    Yb[(size_t)row * 16 + col] = (unsigned short)rne_bf16(acc[r]);
            }
        }
    } else {
        // ---- binA: bucket the edges; packed = (src<<9)|(dst&511) ----
        const int b2 = blk - GEMM_BLKS;           // 0..255
        const int lo = b2 * EPB, hi = lo + EPB;
        int v = (t < NBUCK) ? cntA[t] : 0;
        sm.a.sscan[t] = v;
        __syncthreads();
        for (int off = 1; off < 256; off <<= 1) {
            int u = (t >= off) ? sm.a.sscan[t - off] : 0;
            __syncthreads();
            sm.a.sscan[t] += u;
            __syncthreads();
        }
        if (t < NBUCK) { sm.a.baseL[t] = sm.a.sscan[t] - v; sm.a.hist[t] = 0; }
        __syncthreads();
        for (int i = lo + t; i < hi; i += 256)
            atomicAdd(&sm.a.hist[dst[i] >> 9], 1);
        __syncthreads();
        if (t < NBUCK) {
            int c = sm.a.hist[t];
            sm.a.hist[t] = c ? sm.a.baseL[t] + atomicAdd(&cursorCnt[t], c) : 0;
        }
        __syncthreads();
        for (int i = lo + t; i < hi; i += 256) {
            int d = dst[i];
            int pos = atomicAdd(&sm.a.hist[d >> 9], 1);
            packed[pos] = ((unsigned)src[i] << 9) | (unsigned)(d & 511);
        }
    }
    __threadfence();
    grid.sync();

    // ======================= P1: binB =======================
    if (blk < NBUCK) {
        int v = (t < NBUCK) ? cntA[t] : 0;
        sm.b.sscan[t] = v;
        __syncthreads();
        for (int off = 1; off < 256; off <<= 1) {
            int u = (t >= off) ? sm.b.sscan[t - off] : 0;
            __syncthreads();
            sm.b.sscan[t] += u;
            __syncthreads();
        }
        const int hi = sm.b.sscan[blk];
        const int lo = hi - cntA[blk];

        sm.b.h[t] = 0; sm.b.h[t + 256] = 0;
        __syncthreads();
        for (int i = lo + t; i < hi; i += 256)
            atomicAdd(&sm.b.h[packed[i] & 511], 1);
        __syncthreads();
        int m0 = sm.b.h[t], m1 = sm.b.h[t + 256];
        for (int off = 1; off < 512; off <<= 1) {
            int u0 = (t >= off) ? sm.b.h[t - off] : 0;
            int u1 = (t + 256 >= off) ? sm.b.h[t + 256 - off] : 0;
            __syncthreads();
            sm.b.h[t] += u0;
            sm.b.h[t + 256] += u1;
            __syncthreads();
        }
        int g0 = lo + sm.b.h[t] - m0;         // exclusive prefix
        int g1 = lo + sm.b.h[t + 256] - m1;
        int n0 = blk * BS + t, n1 = blk * BS + t + 256;
        if (n0 < NN) offs[n0] = g0;
        if (n1 < NN) offs[n1] = g1;
        sm.b.run[t] = g0; sm.b.run[t + 256] = g1;
        __syncthreads();
        for (int i = lo + t; i < hi; i += 256) {
            unsigned v2 = packed[i];
            int pos = atomicAdd(&sm.b.run[v2 & 511], 1);
            srcs[pos] = (int)(v2 >> 9);
        }
        if (blk == 0 && t == 0) offs[NN] = NE;
    }
    __threadfence();
    grid.sync();

    // ======================= P2: Gb = A * Yb =======================
    for (int tid = blk * 256 + t; tid < NN * 4; tid += NBLK * 256)
        agg_body<false>(tid, Yb, offs, srcs, Gb);
    __threadfence();
    grid.sync();

    // ======================= P3: Yb = A * Gb =======================
    for (int tid = blk * 256 + t; tid < NN * 4; tid += NBLK * 256)
        agg_body<false>(tid, Gb, offs, srcs, Yb);
    __threadfence();
    grid.sync();

    // ======================= P4: out = A * Yb (fp32) =======================
    for (int tid = blk * 256 + t; tid < NN * 4; tid += NBLK * 256)
        agg_body<true>(tid, Yb, offs, srcs, out);
}

// ===========================================================================
extern "C" void kernel_launch(void* const* d_in, const int* in_sizes, int n_in,
                              void* d_out, int out_size, void* d_ws, size_t ws_size,
                              hipStream_t stream) {
    const float* X   = (const float*)d_in[0];   // [100000, 512]
    const int*   src = (const int*)d_in[1];     // [3200000]
    const int*   dst = (const int*)d_in[2];     // [3200000]
    const float* W1  = (const float*)d_in[3];   // [512, 256]
    const float* W2  = (const float*)d_in[4];   // [256, 256]
    const float* W3  = (const float*)d_in[5];   // [256, 16]
    float* out = (float*)d_out;                 // [100000, 16]

    char* ws = (char*)d_ws;
    unsigned short* Yb = (unsigned short*)ws;   ws += (size_t)NN * 16 * 2;   // 3.2 MB
    unsigned short* Gb = (unsigned short*)ws;   ws += (size_t)NN * 16 * 2;   // 3.2 MB
    float* M1 = (float*)ws;                     ws += 256 * 16 * 4;
    unsigned short* WcT = (unsigned short*)ws;  ws += 16 * 512 * 2;
    unsigned* packed = (unsigned*)ws;           ws += (size_t)NE * 4;        // 12.8 MB
    int* srcs       = (int*)ws;                 ws += (size_t)NE * 4;        // 12.8 MB
    int* offs       = (int*)ws;                 ws += ((size_t)NN + 4) * 4;  // 400 KB
    int* cntA       = (int*)ws;                 ws += 256 * 4;
    int* cursorCnt  = (int*)ws;                 ws += 256 * 4;

    // zero cntA + cursorCnt (contiguous)
    hipMemsetAsync(cntA, 0, 512 * 4, stream);

    // L1: W2@W3 -> M1  ||  coarse histogram of dst
    l1_gemm_hist<<<16 + 256, 256, 0, stream>>>(W2, W3, M1, dst, cntA);

    // L2: (W1@M1)^T -> WcT bf16
    gemm_n16t<<<32, 256, 0, stream>>>(W1, M1, WcT);

    // Cooperative mega-kernel: {gemm || binA} -> binB -> agg x3
    void* args[] = {(void*)&src, (void*)&dst, (void*)&cntA, (void*)&cursorCnt,
                    (void*)&packed, (void*)&X, (void*)&WcT, (void*)&Yb,
                    (void*)&Gb, (void*)&offs, (void*)&srcs, (void*)&out};
    hipLaunchCooperativeKernel((void*)mega, dim3(NBLK), dim3(256), args, 0, stream);
}

// Round 13
// 235.282 us; speedup vs baseline: 5.0585x; 5.0585x over previous
//
#include <hip/hip_runtime.h>

#define NN 100000
#define NE 3200000
#define BS 512                      // nodes per bucket
#define NBUCK 196                   // ceil(NN/BS); 196*512 = 100352
#define EPB 12500                   // edges per binA block: 256 blocks * 12500 = NE

typedef short bf16x8 __attribute__((ext_vector_type(8)));
typedef float f32x4  __attribute__((ext_vector_type(4)));

__device__ inline unsigned rne_bf16(float x) {
    unsigned u = __float_as_uint(x);
    return (u + 0x7fffu + ((u >> 16) & 1u)) >> 16;   // round-to-nearest-even
}
__device__ inline float bflo(unsigned u) { return __uint_as_float(u << 16); }
__device__ inline float bfhi(unsigned u) { return __uint_as_float(u & 0xffff0000u); }

// ===========================================================================
// L1: fused {gemm_n16 (W2@W3 -> M1), 16 blocks} + {hist_coarse, 256 blocks}
// ===========================================================================
__global__ __launch_bounds__(256) void l1_gemm_hist(const float* __restrict__ W2,
                                                    const float* __restrict__ W3,
                                                    float* __restrict__ M1,
                                                    const int* __restrict__ dst,
                                                    int* __restrict__ cntA) {
    __shared__ float As[16][260];
    __shared__ float Bs[256][16];
    __shared__ int hh[NBUCK];
    const int t = threadIdx.x;

    if (blockIdx.x < 16) {
        const int block_row = blockIdx.x * 16;
        for (int i = t; i < 1024; i += 256)
            ((float4*)&Bs[0][0])[i] = ((const float4*)W3)[i];
        for (int i = t; i < 1024; i += 256) {
            int idx = i << 2;
            int r = idx >> 8, c = idx & 255;
            int row = block_row + r;
            float4 v = ((const float4*)(W2 + (size_t)row * 256))[c >> 2];
            *(float4*)&As[r][c] = v;
        }
        __syncthreads();
        const int r = t >> 4, c = t & 15;
        float acc = 0.f;
#pragma unroll 8
        for (int k = 0; k < 256; ++k) acc += As[r][k] * Bs[k][c];
        M1[(size_t)(block_row + r) * 16 + c] = acc;
    } else {
        const int hb = blockIdx.x - 16;   // 0..255
        for (int i = t; i < NBUCK; i += 256) hh[i] = 0;
        __syncthreads();
        for (int e = hb * 256 + t; e < NE; e += 256 * 256)
            atomicAdd(&hh[dst[e] >> 9], 1);
        __syncthreads();
        for (int i = t; i < NBUCK; i += 256)
            if (hh[i]) atomicAdd(&cntA[i], hh[i]);
    }
}

// ===========================================================================
// L2: gemm_n16t: WcT[16][512] bf16 = (W1[512][256] @ M1[256][16])^T
// ===========================================================================
__global__ __launch_bounds__(256) void gemm_n16t(const float* __restrict__ A,
                                                 const float* __restrict__ B,
                                                 unsigned short* __restrict__ Wt) {
    __shared__ float As[16][260];
    __shared__ float Bs[256][16];
    const int t = threadIdx.x;
    const int block_row = blockIdx.x * 16;

    for (int i = t; i < 1024; i += 256)
        ((float4*)&Bs[0][0])[i] = ((const float4*)B)[i];
    for (int i = t; i < 1024; i += 256) {
        int idx = i << 2;
        int r = idx >> 8, c = idx & 255;
        int row = block_row + r;
        float4 v = ((const float4*)(A + (size_t)row * 256))[c >> 2];
        *(float4*)&As[r][c] = v;
    }
    __syncthreads();
    const int r = t >> 4, c = t & 15;
    float acc = 0.f;
#pragma unroll 8
    for (int k = 0; k < 256; ++k) acc += As[r][k] * Bs[k][c];
    Wt[(size_t)c * 512 + block_row + r] = (unsigned short)rne_bf16(acc);
}

// ===========================================================================
// binA: bucket the edges; packed = (src<<9)|(dst&511)
// ===========================================================================
__global__ __launch_bounds__(512) void binA(const int* __restrict__ src,
                                            const int* __restrict__ dst,
                                            const int* __restrict__ cntA,
                                            int* __restrict__ cursorCnt,
                                            unsigned* __restrict__ packed) {
    __shared__ int sscan[256];
    __shared__ int baseL[NBUCK];
    __shared__ int hist[NBUCK];
    const int t = threadIdx.x;
    const int lo = blockIdx.x * EPB, hi = lo + EPB;

    int v = 0;
    if (t < 256) { v = (t < NBUCK) ? cntA[t] : 0; sscan[t] = v; }
    __syncthreads();
    for (int off = 1; off < 256; off <<= 1) {
        int u = 0;
        if (t < 256 && t >= off) u = sscan[t - off];
        __syncthreads();
        if (t < 256) sscan[t] += u;
        __syncthreads();
    }
    if (t < NBUCK) baseL[t] = sscan[t] - v;
    for (int i = t; i < NBUCK; i += 512) hist[i] = 0;
    __syncthreads();
    for (int i = lo + t; i < hi; i += 512)
        atomicAdd(&hist[dst[i] >> 9], 1);
    __syncthreads();
    for (int i = t; i < NBUCK; i += 512) {
        int c = hist[i];
        hist[i] = c ? baseL[i] + atomicAdd(&cursorCnt[i], c) : 0;
    }
    __syncthreads();
    for (int i = lo + t; i < hi; i += 512) {
        int d = dst[i];
        int pos = atomicAdd(&hist[d >> 9], 1);
        packed[pos] = ((unsigned)src[i] << 9) | (unsigned)(d & 511);
    }
}

// ===========================================================================
// gemm_xwc: Yb[NN][16] bf16 = bf16(X[NN][512]) @ WcT^T; LDS-staged MFMA
// ===========================================================================
__global__ __launch_bounds__(512) void gemm_xwc(const float* __restrict__ X,
                                                const unsigned short* __restrict__ WcT,
                                                unsigned short* __restrict__ Yb) {
    __shared__ unsigned short As[128][72];
    __shared__ unsigned short Ws[16][520];

    const int t = threadIdx.x;
    const int brow = blockIdx.x * 128;
    const int w = t >> 6, lane = t & 63;
    const int lrow = lane & 15, lk8 = (lane >> 4) * 8;

    for (int idx = t; idx < 1024; idx += 512) {
        int row = idx >> 6, ch = idx & 63;
        *(uint4*)&Ws[row][ch * 8] = ((const uint4*)(WcT + row * 512))[ch];
    }

    const int s_arow = t & 127, s_aq = t >> 7;
    const bool arow_ok = (brow + s_arow) < NN;
    const float* Ap0 = X + (size_t)(brow + s_arow) * 512 + s_aq * 16;

    f32x4 acc = {};

    for (int k0 = 0; k0 < 512; k0 += 64) {
        float4 f[4];
        if (arow_ok) {
            const float4* p = (const float4*)(Ap0 + k0);
#pragma unroll
            for (int i = 0; i < 4; ++i) f[i] = p[i];
        } else {
#pragma unroll
            for (int i = 0; i < 4; ++i) f[i] = make_float4(0.f, 0.f, 0.f, 0.f);
        }
        unsigned p8[8];
#pragma unroll
        for (int i = 0; i < 4; ++i) {
            p8[2 * i]     = rne_bf16(f[i].x) | (rne_bf16(f[i].y) << 16);
            p8[2 * i + 1] = rne_bf16(f[i].z) | (rne_bf16(f[i].w) << 16);
        }
        *(uint4*)&As[s_arow][s_aq * 16]     = make_uint4(p8[0], p8[1], p8[2], p8[3]);
        *(uint4*)&As[s_arow][s_aq * 16 + 8] = make_uint4(p8[4], p8[5], p8[6], p8[7]);
        __syncthreads();

#pragma unroll
        for (int ks = 0; ks < 2; ++ks) {
            bf16x8 af = *(const bf16x8*)&As[w * 16 + lrow][ks * 32 + lk8];
            bf16x8 bw = *(const bf16x8*)&Ws[lrow][k0 + ks * 32 + lk8];
            acc = __builtin_amdgcn_mfma_f32_16x16x32_bf16(af, bw, acc, 0, 0, 0);
        }
        __syncthreads();
    }

    const int col = lrow;
    const int rbase = brow + w * 16 + (lane >> 4) * 4;
#pragma unroll
    for (int r = 0; r < 4; ++r) {
        int row = rbase + r;
        if (row < NN)
            Yb[(size_t)row * 16 + col] = (unsigned short)rne_bf16(acc[r]);
    }
}

// ===========================================================================
// binB: per-bucket counting sort -> offs + srcs (one block per bucket)
// ===========================================================================
__global__ __launch_bounds__(512) void binB(const unsigned* __restrict__ packed,
                                            const int* __restrict__ cntA,
                                            int* __restrict__ offs,
                                            int* __restrict__ srcs) {
    __shared__ int sscan[256];
    __shared__ int h[512];
    __shared__ int run[512];
    const int b = blockIdx.x, t = threadIdx.x;

    int v = 0;
    if (t < 256) { v = (t < NBUCK) ? cntA[t] : 0; sscan[t] = v; }
    __syncthreads();
    for (int off = 1; off < 256; off <<= 1) {
        int u = 0;
        if (t < 256 && t >= off) u = sscan[t - off];
        __syncthreads();
        if (t < 256) sscan[t] += u;
        __syncthreads();
    }
    const int hi = sscan[b];
    const int lo = hi - cntA[b];

    h[t] = 0;
    __syncthreads();
    for (int i = lo + t; i < hi; i += 512)
        atomicAdd(&h[packed[i] & 511], 1);
    __syncthreads();
    int mine = h[t];
    for (int off = 1; off < 512; off <<= 1) {
        int u = (t >= off) ? h[t - off] : 0;
        __syncthreads();
        h[t] += u;
        __syncthreads();
    }
    int gbase = lo + (h[t] - mine);
    int node = b * BS + t;
    if (node < NN) offs[node] = gbase;
    run[t] = gbase;
    __syncthreads();
    for (int i = lo + t; i < hi; i += 512) {
        unsigned v2 = packed[i];
        int pos = atomicAdd(&run[v2 & 511], 1);
        srcs[pos] = (int)(v2 >> 9);
    }
    if (b == NBUCK - 1 && t == 0) offs[NN] = NE;
}

// ===========================================================================
// Aggregation: bf16 gather, fp32 accumulate; 4 threads/node, uint2 (4 feats)
// UNROLL-4: four independent load->gather chains to hide L2 latency
// ===========================================================================
template<bool OUT_F32>
__global__ __launch_bounds__(256) void agg16(const unsigned short* __restrict__ h,
                                             const int* __restrict__ offs,
                                             const int* __restrict__ srcs,
                                             void* __restrict__ outp) {
    int tid = blockIdx.x * 256 + threadIdx.x;
    int node = tid >> 2, f4 = tid & 3;
    if (node >= NN) return;
    int beg = offs[node], end = offs[node + 1];
    float a0 = 0, a1 = 0, a2 = 0, a3 = 0;
    float b0 = 0, b1 = 0, b2 = 0, b3 = 0;
    float c0 = 0, c1 = 0, c2 = 0, c3 = 0;
    float d0 = 0, d1 = 0, d2 = 0, d3 = 0;
    int j = beg;
    for (; j + 4 <= end; j += 4) {
        int s0 = srcs[j], s1 = srcs[j + 1], s2 = srcs[j + 2], s3 = srcs[j + 3];
        uint2 u = *(const uint2*)(h + (size_t)s0 * 16 + f4 * 4);
        uint2 v = *(const uint2*)(h + (size_t)s1 * 16 + f4 * 4);
        uint2 w = *(const uint2*)(h + (size_t)s2 * 16 + f4 * 4);
        uint2 x = *(const uint2*)(h + (size_t)s3 * 16 + f4 * 4);
        a0 += bflo(u.x); a1 += bfhi(u.x); a2 += bflo(u.y); a3 += bfhi(u.y);
        b0 += bflo(v.x); b1 += bfhi(v.x); b2 += bflo(v.y); b3 += bfhi(v.y);
        c0 += bflo(w.x); c1 += bfhi(w.x); c2 += bflo(w.y); c3 += bfhi(w.y);
        d0 += bflo(x.x); d1 += bfhi(x.x); d2 += bflo(x.y); d3 += bfhi(x.y);
    }
    for (; j < end; ++j) {
        uint2 u = *(const uint2*)(h + (size_t)srcs[j] * 16 + f4 * 4);
        a0 += bflo(u.x); a1 += bfhi(u.x); a2 += bflo(u.y); a3 += bfhi(u.y);
    }
    float r0 = (a0 + b0) + (c0 + d0);
    float r1 = (a1 + b1) + (c1 + d1);
    float r2 = (a2 + b2) + (c2 + d2);
    float r3 = (a3 + b3) + (c3 + d3);
    if (OUT_F32) {
        ((float4*)outp)[(size_t)node * 4 + f4] = make_float4(r0, r1, r2, r3);
    } else {
        uint2 r;
        r.x = rne_bf16(r0) | (rne_bf16(r1) << 16);
        r.y = rne_bf16(r2) | (rne_bf16(r3) << 16);
        ((uint2*)outp)[(size_t)node * 4 + f4] = r;
    }
}

// ===========================================================================
extern "C" void kernel_launch(void* const* d_in, const int* in_sizes, int n_in,
                              void* d_out, int out_size, void* d_ws, size_t ws_size,
                              hipStream_t stream) {
    const float* X   = (const float*)d_in[0];   // [100000, 512]
    const int*   src = (const int*)d_in[1];     // [3200000]
    const int*   dst = (const int*)d_in[2];     // [3200000]
    const float* W1  = (const float*)d_in[3];   // [512, 256]
    const float* W2  = (const float*)d_in[4];   // [256, 256]
    const float* W3  = (const float*)d_in[5];   // [256, 16]
    float* out = (float*)d_out;                 // [100000, 16]

    char* ws = (char*)d_ws;
    unsigned short* Yb = (unsigned short*)ws;   ws += (size_t)NN * 16 * 2;   // 3.2 MB
    unsigned short* Gb = (unsigned short*)ws;   ws += (size_t)NN * 16 * 2;   // 3.2 MB
    float* M1 = (float*)ws;                     ws += 256 * 16 * 4;
    unsigned short* WcT = (unsigned short*)ws;  ws += 16 * 512 * 2;
    unsigned* packed = (unsigned*)ws;           ws += (size_t)NE * 4;        // 12.8 MB
    int* srcs       = (int*)ws;                 ws += (size_t)NE * 4;        // 12.8 MB
    int* offs       = (int*)ws;                 ws += ((size_t)NN + 4) * 4;  // 400 KB
    int* cntA       = (int*)ws;                 ws += 256 * 4;
    int* cursorCnt  = (int*)ws;                 ws += 256 * 4;

    // zero cntA + cursorCnt (contiguous)
    hipMemsetAsync(cntA, 0, 512 * 4, stream);

    // L1: W2@W3 -> M1  ||  coarse histogram of dst
    l1_gemm_hist<<<16 + 256, 256, 0, stream>>>(W2, W3, M1, dst, cntA);

    // L2: (W1@M1)^T -> WcT bf16
    gemm_n16t<<<32, 256, 0, stream>>>(W1, M1, WcT);

    // binA: bucket the edges
    binA<<<256, 512, 0, stream>>>(src, dst, cntA, cursorCnt, packed);

    // Yb = bf16(X @ Wc)
    gemm_xwc<<<(NN + 127) / 128, 512, 0, stream>>>(X, WcT, Yb);

    // binB: per-bucket counting sort -> offs, srcs
    binB<<<NBUCK, 512, 0, stream>>>(packed, cntA, offs, srcs);

    // out = A^3 Y : three width-16 aggregations (bf16, bf16, fp32-out)
    const int agg_blocks = (NN * 4 + 255) / 256;   // 1563
    agg16<false><<<agg_blocks, 256, 0, stream>>>(Yb, offs, srcs, Gb);
    agg16<false><<<agg_blocks, 256, 0, stream>>>(Gb, offs, srcs, Yb);
    agg16<true ><<<agg_blocks, 256, 0, stream>>>(Yb, offs, srcs, out);
}